// Round 11
// baseline (110.813 us; speedup 1.0000x reference)
//
#include <hip/hip_runtime.h>
#include <hip/hip_bf16.h>

#define NHEADS 6
#define HD 32
#define CDIM 192
#define NTOK 64
#define NREL 225
#define PDIM 12
#define IMG 256
#define NWIN 2048
#define QSCALE 0.2550348686f      // 32^-0.5 * log2(e)
#define LOG2E 1.4426950408889634f

typedef __attribute__((ext_vector_type(8))) short v8s;
typedef __attribute__((ext_vector_type(4))) float v4f;

#define KS2 200  // ks row stride (ushort): 400B
#define VTS 72   // vt row stride: 144B

__device__ __forceinline__ unsigned pkbf(float x, float y) {
    __hip_bfloat162 h = __float22bfloat162_rn(make_float2(x, y));
    union { __hip_bfloat162 h; unsigned u; } c; c.h = h;
    return c.u;
}

__device__ __forceinline__ float ex2(float x) {
    float r; asm("v_exp_f32 %0, %1" : "=v"(r) : "v"(x)); return r;
}

__device__ __forceinline__ void ln_relu12(const float* x, const float* g,
                                          const float* be, float* y) {
    float m = 0.f;
#pragma unroll
    for (int i = 0; i < PDIM; ++i) m += x[i];
    m *= (1.f / PDIM);
    float v = 0.f;
#pragma unroll
    for (int i = 0; i < PDIM; ++i) { float d = x[i] - m; v += d * d; }
    v *= (1.f / PDIM);
    float inv = rsqrtf(v + 1e-5f);
#pragma unroll
    for (int i = 0; i < PDIM; ++i) {
        float t = (x[i] - m) * inv * g[i] + be[i];
        y[i] = t > 0.f ? t : 0.f;
    }
}

__global__ __launch_bounds__(512, 4) void win_attn_fused(
    const float* __restrict__ qkv,
    const float* __restrict__ wp, const float* __restrict__ bp,
    const float* __restrict__ g1, const float* __restrict__ be1,
    const float* __restrict__ w1, const float* __restrict__ b1,
    const float* __restrict__ g2, const float* __restrict__ be2,
    const float* __restrict__ w2, const float* __restrict__ b2,
    const float* __restrict__ g3, const float* __restrict__ be3,
    const float* __restrict__ w3, const float* __restrict__ b3,
    float* __restrict__ out)
{
    __shared__ __align__(16) unsigned short ks[NTOK * KS2];  // K, all heads
    __shared__ __align__(16) unsigned short vt[CDIM * VTS];  // V^T in k' order
    __shared__ __align__(16) float pshf[NREL * 8];           // bias [idx][8]

    const int t = threadIdx.x;
    const int win = blockIdx.x;
    const int b  = win >> 10;
    const int bh = (win >> 5) & 31;
    const int bw = win & 31;

    const int lane = t & 63;
    const int wave = t >> 6;          // 0..7
    const int rg   = wave & 3;
    const int hh   = wave >> 2;       // 0: heads 0-2, 1: heads 3-5
    const int hbase = hh * 3;
    const int lw = lane & 15;
    const int lg = lane >> 4;
    const int rowbase = rg * 16;

    const size_t PL = (size_t)2 * IMG * IMG * CDIM;
    const float* qplane = qkv + (size_t)b * IMG * IMG * CDIM;
    const float* kplane = qplane + PL;
    const float* vplane = kplane + PL;

    auto pixoff = [&](int tok) -> size_t {
        return ((size_t)(bh * 8 + (tok >> 3)) * IMG + (bw * 8 + (tok & 7))) * CDIM;
    };

    // ---------- issue K loads (contiguous streaming) ----------
    float4 kreg[6];
    int kidx[6][2];
#pragma unroll
    for (int pass = 0; pass < 6; ++pass) {
        int fidx = t + pass * 512;            // 0..3071
        int s   = fidx / 384;
        int rem = fidx - s * 384;
        int j1  = rem / 48;
        int f   = rem - j1 * 48;
        kreg[pass] = *(const float4*)(kplane
                     + ((size_t)(bh * 8 + s) * IMG + (bw * 8 + j1)) * CDIM + f * 4);
        kidx[pass][0] = s * 8 + j1;
        kidx[pass][1] = f * 4;
    }

    // ---------- issue V loads -> regs (consumed AFTER QK phase) ----------
    const int tp = t & 31;                    // token pair (2tp, 2tp+1)
    const int g  = t >> 5;                    // 0..15
    const int tok0 = 2 * tp;
    float4 vA[3], vB[3];
    {
        const size_t offa = pixoff(tok0), offb = pixoff(tok0 + 1);
#pragma unroll
        for (int i = 0; i < 3; ++i) {
            int f = g + i * 16;               // float4 slot 0..47
            vA[i] = *(const float4*)(vplane + offa + f * 4);
            vB[i] = *(const float4*)(vplane + offb + f * 4);
        }
    }

    // ---------- Q loads + convert (pre-scaled by SCALE*log2e) ----------
    v8s aq[3];
    {
        const size_t qoff = pixoff(rowbase + lw);
#pragma unroll
        for (int hi = 0; hi < 3; ++hi) {
            const float* qp = qplane + qoff + (hbase + hi) * HD + lg * 8;
            float4 q0 = *(const float4*)qp;
            float4 q1 = *(const float4*)(qp + 4);
            union { v8s v; unsigned x[4]; } au;
            au.x[0] = pkbf(q0.x * QSCALE, q0.y * QSCALE);
            au.x[1] = pkbf(q0.z * QSCALE, q0.w * QSCALE);
            au.x[2] = pkbf(q1.x * QSCALE, q1.y * QSCALE);
            au.x[3] = pkbf(q1.z * QSCALE, q1.w * QSCALE);
            aq[hi] = au.v;
        }
    }

    // ---------- fused MLP: bias * log2e, [idx][8] with hh-swizzle ----------
    if (t < NREL) {
        float x0 = (float)(t / 15 - 7);
        float x1 = (float)(t % 15 - 7);
        float h[PDIM], y[PDIM];
#pragma unroll
        for (int o = 0; o < PDIM; ++o)
            h[o] = x0 * wp[o] + x1 * wp[PDIM + o] + bp[o];
        ln_relu12(h, g1, be1, y);
#pragma unroll
        for (int o = 0; o < PDIM; ++o) {
            float a = b1[o];
#pragma unroll
            for (int i = 0; i < PDIM; ++i) a += y[i] * w1[i * PDIM + o];
            h[o] = a;
        }
        ln_relu12(h, g2, be2, y);
#pragma unroll
        for (int o = 0; o < PDIM; ++o) {
            float a = b2[o];
#pragma unroll
            for (int i = 0; i < PDIM; ++i) a += y[i] * w2[i * PDIM + o];
            h[o] = a;
        }
        ln_relu12(h, g3, be3, y);
        const int sw = (t >> 2) & 1;
#pragma unroll
        for (int o = 0; o < NHEADS; ++o) {
            float a = b3[o];
#pragma unroll
            for (int i = 0; i < PDIM; ++i) a += y[i] * w3[i * NHEADS + o];
            int half = (o >= 3) ? 1 : 0;
            pshf[(t * 2 + (half ^ sw)) * 4 + (o - half * 3)] = a * LOG2E;
        }
    }

    // ---------- K convert + write ----------
#pragma unroll
    for (int pass = 0; pass < 6; ++pass) {
        uint2 kk;
        kk.x = pkbf(kreg[pass].x, kreg[pass].y);
        kk.y = pkbf(kreg[pass].z, kreg[pass].w);
        *(uint2*)&ks[kidx[pass][0] * KS2 + kidx[pass][1]] = kk;
    }
    __syncthreads();   // bar1: ks + pshf visible (V still in flight)

    // ---------- S^T = mfma(K, Q): lane holds q-row lw, tok = ct*16+lg*4+r ----------
    v4f acc[3][4];
#pragma unroll
    for (int ct = 0; ct < 4; ++ct) {
#pragma unroll
        for (int hi = 0; hi < 3; ++hi) {
            v4f z = {0.f, 0.f, 0.f, 0.f};
            v8s bfr = *(const v8s*)&ks[(ct * 16 + lw) * KS2 + (hbase + hi) * HD + lg * 8];
            acc[hi][ct] = __builtin_amdgcn_mfma_f32_16x16x32_bf16(bfr, aq[hi], z, 0, 0, 0);
        }
    }

    // ---------- bias + exp2 ----------
    {
        const int q = rowbase + lw;
        const int base2 = ((q >> 3) + 7) * 15 + (q & 7) + 7
                        - ((lg >> 1) * 15 + (lg & 1) * 4);
#pragma unroll
        for (int ct = 0; ct < 4; ++ct)
#pragma unroll
            for (int r = 0; r < 4; ++r) {
                int idx = base2 - ct * 30 - r;
                const float4 bb = *(const float4*)&pshf[(idx * 2 + (hh ^ ((idx >> 2) & 1))) * 4];
                acc[0][ct][r] = ex2(acc[0][ct][r] + bb.x);
                acc[1][ct][r] = ex2(acc[1][ct][r] + bb.y);
                acc[2][ct][r] = ex2(acc[2][ct][r] + bb.z);
            }
    }

    // ---------- row-sum (in-lane + 2 shuffles), normalize into PA pack ----------
    unsigned pa[3][2][4];   // [head][kt][4x u32 of bf16x2] = PV A-fragments
#pragma unroll
    for (int hi = 0; hi < 3; ++hi) {
        float s = 0.f;
#pragma unroll
        for (int ct = 0; ct < 4; ++ct)
#pragma unroll
            for (int r = 0; r < 4; ++r) s += acc[hi][ct][r];
        s += __shfl_xor(s, 16);
        s += __shfl_xor(s, 32);
        float rv = __builtin_amdgcn_rcpf(s);
#pragma unroll
        for (int kt = 0; kt < 2; ++kt) {
            pa[hi][kt][0] = pkbf(acc[hi][2*kt][0] * rv, acc[hi][2*kt][1] * rv);
            pa[hi][kt][1] = pkbf(acc[hi][2*kt][2] * rv, acc[hi][2*kt][3] * rv);
            pa[hi][kt][2] = pkbf(acc[hi][2*kt+1][0] * rv, acc[hi][2*kt+1][1] * rv);
            pa[hi][kt][3] = pkbf(acc[hi][2*kt+1][2] * rv, acc[hi][2*kt+1][3] * rv);
        }
    }

    // ---------- V convert + write (k' layout); loads hidden under QK ----------
    {
        // k'(tok) = (tok>>5)*32 + ((tok>>2)&3)*8 + ((tok>>4)&1)*4 + (tok&3)
        const int k0 = ((tok0 >> 5) << 5) + (((tok0 >> 2) & 3) << 3)
                     + (((tok0 >> 4) & 1) << 2) + (tok0 & 3);
#pragma unroll
        for (int i = 0; i < 3; ++i) {
            int d0 = (g + i * 16) * 4;
            *(unsigned*)&vt[(d0 + 0) * VTS + k0] = pkbf(vA[i].x, vB[i].x);
            *(unsigned*)&vt[(d0 + 1) * VTS + k0] = pkbf(vA[i].y, vB[i].y);
            *(unsigned*)&vt[(d0 + 2) * VTS + k0] = pkbf(vA[i].z, vB[i].z);
            *(unsigned*)&vt[(d0 + 3) * VTS + k0] = pkbf(vA[i].w, vB[i].w);
        }
    }
    __syncthreads();   // bar2: vt visible

    // ---------- output offsets ----------
    size_t ooff[4];
#pragma unroll
    for (int r = 0; r < 4; ++r) {
        int n = rowbase + lg * 4 + r;
        ooff[r] = ((size_t)(b * IMG + bh * 8 + (n >> 3)) * IMG
                   + (bw * 8 + (n & 7))) * CDIM;
    }

    // ---------- O = P_norm V ----------
#pragma unroll
    for (int hi = 0; hi < 3; ++hi) {
        const int h = hbase + hi;
        v4f acc2[2] = {};
#pragma unroll
        for (int kt = 0; kt < 2; ++kt) {
            v8s pav = *(const v8s*)&pa[hi][kt][0];
#pragma unroll
            for (int dt = 0; dt < 2; ++dt) {
                v8s vb = *(const v8s*)&vt[(h * HD + dt * 16 + lw) * VTS
                                          + kt * 32 + lg * 8];
                acc2[dt] = __builtin_amdgcn_mfma_f32_16x16x32_bf16(pav, vb, acc2[dt], 0, 0, 0);
            }
        }
#pragma unroll
        for (int dt = 0; dt < 2; ++dt)
#pragma unroll
            for (int r = 0; r < 4; ++r)
                out[ooff[r] + h * HD + dt * 16 + lw] = acc2[dt][r];
    }
}

extern "C" void kernel_launch(void* const* d_in, const int* in_sizes, int n_in,
                              void* d_out, int out_size, void* d_ws, size_t ws_size,
                              hipStream_t stream) {
    const float* qkv = (const float*)d_in[0];
    win_attn_fused<<<NWIN, 512, 0, stream>>>(
        qkv,
        (const float*)d_in[1], (const float*)d_in[2],
        (const float*)d_in[3], (const float*)d_in[4],
        (const float*)d_in[5], (const float*)d_in[6],
        (const float*)d_in[7], (const float*)d_in[8],
        (const float*)d_in[9], (const float*)d_in[10],
        (const float*)d_in[11], (const float*)d_in[12],
        (const float*)d_in[13], (const float*)d_in[14],
        (float*)d_out);
}

// Round 12
// 84.323 us; speedup vs baseline: 1.3142x; 1.3142x over previous
//
#include <hip/hip_runtime.h>
#include <hip/hip_bf16.h>

#define NHEADS 6
#define HD 32
#define CDIM 192
#define NTOK 64
#define NREL 225
#define PDIM 12
#define IMG 256
#define NWIN 2048
#define QSCALE 0.2550348686f      // 32^-0.5 * log2(e)
#define LOG2E 1.4426950408889634f

typedef __attribute__((ext_vector_type(8))) short v8s;
typedef __attribute__((ext_vector_type(4))) float v4f;

#define KS3 104  // ks row stride (ushort): 96 ch + 8 pad = 208B
#define VTS 72   // vt row stride: 144B

__device__ __forceinline__ unsigned pkbf(float x, float y) {
    __hip_bfloat162 h = __float22bfloat162_rn(make_float2(x, y));
    union { __hip_bfloat162 h; unsigned u; } c; c.h = h;
    return c.u;
}

__device__ __forceinline__ float ex2(float x) {
    float r; asm("v_exp_f32 %0, %1" : "=v"(r) : "v"(x)); return r;
}

__device__ __forceinline__ void ln_relu12(const float* x, const float* g,
                                          const float* be, float* y) {
    float m = 0.f;
#pragma unroll
    for (int i = 0; i < PDIM; ++i) m += x[i];
    m *= (1.f / PDIM);
    float v = 0.f;
#pragma unroll
    for (int i = 0; i < PDIM; ++i) { float d = x[i] - m; v += d * d; }
    v *= (1.f / PDIM);
    float inv = rsqrtf(v + 1e-5f);
#pragma unroll
    for (int i = 0; i < PDIM; ++i) {
        float t = (x[i] - m) * inv * g[i] + be[i];
        y[i] = t > 0.f ? t : 0.f;
    }
}

__global__ __launch_bounds__(256, 4) void win_attn_fused(
    const float* __restrict__ qkv,
    const float* __restrict__ wp, const float* __restrict__ bp,
    const float* __restrict__ g1, const float* __restrict__ be1,
    const float* __restrict__ w1, const float* __restrict__ b1,
    const float* __restrict__ g2, const float* __restrict__ be2,
    const float* __restrict__ w2, const float* __restrict__ b2,
    const float* __restrict__ g3, const float* __restrict__ be3,
    const float* __restrict__ w3, const float* __restrict__ b3,
    float* __restrict__ out)
{
    __shared__ __align__(16) unsigned short ks[NTOK * KS3];  // K half (3 heads)
    __shared__ __align__(16) unsigned short vt[96 * VTS];    // V^T half, k' order
    __shared__ __align__(16) float pshf[NREL * 4];           // bias [idx][4]

    const int t = threadIdx.x;
    const int bid = blockIdx.x;
    const int win = bid >> 1;         // adjacent blocks share a window (pages)
    const int hg  = bid & 1;          // head-group: heads hg*3 .. hg*3+2
    const int b  = win >> 10;
    const int bh = (win >> 5) & 31;
    const int bw = win & 31;

    const int lane = t & 63;
    const int rg   = t >> 6;          // wave = row-group 0..3
    const int lw = lane & 15;
    const int lg = lane >> 4;
    const int rowbase = rg * 16;
    const int hoff = hg * 96;         // channel offset of this head-group

    const size_t PL = (size_t)2 * IMG * IMG * CDIM;
    const float* qplane = qkv + (size_t)b * IMG * IMG * CDIM;
    const float* kplane = qplane + PL;
    const float* vplane = kplane + PL;

    auto pixoff = [&](int tok) -> size_t {
        return ((size_t)(bh * 8 + (tok >> 3)) * IMG + (bw * 8 + (tok & 7))) * CDIM;
    };

    // ---------- K: issue 6 contiguous loads (384B runs per pixel-half) ----------
    float4 kreg[6];
    int kpix[6], kf[6];
#pragma unroll
    for (int pass = 0; pass < 6; ++pass) {
        int fidx = t + pass * 256;            // 0..1535
        int pix = fidx / 24;                  // 0..63
        int f   = fidx - pix * 24;            // 0..23 (float4 in 96-f32 half)
        kreg[pass] = *(const float4*)(kplane + pixoff(pix) + hoff + f * 4);
        kpix[pass] = pix; kf[pass] = f;
    }
    // convert + write immediately (short reg residency)
#pragma unroll
    for (int pass = 0; pass < 6; ++pass) {
        uint2 kk;
        kk.x = pkbf(kreg[pass].x, kreg[pass].y);
        kk.y = pkbf(kreg[pass].z, kreg[pass].w);
        *(uint2*)&ks[kpix[pass] * KS3 + kf[pass] * 4] = kk;
    }

    // ---------- V: k'-paired transpose (conflict-free b32 writes) ----------
    {
        const int tp = t & 31;                // token pair (2tp, 2tp+1)
        const int g  = t >> 5;                // 0..7
        const int tok0 = 2 * tp;
        // k'(tok) = (tok>>5)*32 + ((tok>>2)&3)*8 + ((tok>>4)&1)*4 + (tok&3)
        const int k0 = ((tok0 >> 5) << 5) + (((tok0 >> 2) & 3) << 3)
                     + (((tok0 >> 4) & 1) << 2) + (tok0 & 3);
        const size_t offa = pixoff(tok0) + hoff, offb = pixoff(tok0 + 1) + hoff;
#pragma unroll
        for (int i = 0; i < 3; ++i) {
            int f = g + i * 8;                // float4 slot 0..23
            float4 vA = *(const float4*)(vplane + offa + f * 4);
            float4 vB = *(const float4*)(vplane + offb + f * 4);
            int d0 = f * 4;
            *(unsigned*)&vt[(d0 + 0) * VTS + k0] = pkbf(vA.x, vB.x);
            *(unsigned*)&vt[(d0 + 1) * VTS + k0] = pkbf(vA.y, vB.y);
            *(unsigned*)&vt[(d0 + 2) * VTS + k0] = pkbf(vA.z, vB.z);
            *(unsigned*)&vt[(d0 + 3) * VTS + k0] = pkbf(vA.w, vB.w);
        }
    }

    // ---------- Q: this block's 3 heads, pre-scaled by SCALE*log2e ----------
    v8s aq[3];
    {
        const size_t qoff = pixoff(rowbase + lw) + hoff;
#pragma unroll
        for (int hi = 0; hi < 3; ++hi) {
            const float* qp = qplane + qoff + hi * HD + lg * 8;
            float4 q0 = *(const float4*)qp;
            float4 q1 = *(const float4*)(qp + 4);
            union { v8s v; unsigned x[4]; } au;
            au.x[0] = pkbf(q0.x * QSCALE, q0.y * QSCALE);
            au.x[1] = pkbf(q0.z * QSCALE, q0.w * QSCALE);
            au.x[2] = pkbf(q1.x * QSCALE, q1.y * QSCALE);
            au.x[3] = pkbf(q1.z * QSCALE, q1.w * QSCALE);
            aq[hi] = au.v;
        }
    }

    // ---------- fused MLP: only this block's 3 head-columns ----------
    if (t < NREL) {
        float x0 = (float)(t / 15 - 7);
        float x1 = (float)(t % 15 - 7);
        float h[PDIM], y[PDIM];
#pragma unroll
        for (int o = 0; o < PDIM; ++o)
            h[o] = x0 * wp[o] + x1 * wp[PDIM + o] + bp[o];
        ln_relu12(h, g1, be1, y);
#pragma unroll
        for (int o = 0; o < PDIM; ++o) {
            float a = b1[o];
#pragma unroll
            for (int i = 0; i < PDIM; ++i) a += y[i] * w1[i * PDIM + o];
            h[o] = a;
        }
        ln_relu12(h, g2, be2, y);
#pragma unroll
        for (int o = 0; o < PDIM; ++o) {
            float a = b2[o];
#pragma unroll
            for (int i = 0; i < PDIM; ++i) a += y[i] * w2[i * PDIM + o];
            h[o] = a;
        }
        ln_relu12(h, g3, be3, y);
#pragma unroll
        for (int hi = 0; hi < 3; ++hi) {
            int o = hg * 3 + hi;
            float a = b3[o];
#pragma unroll
            for (int i = 0; i < PDIM; ++i) a += y[i] * w3[i * NHEADS + o];
            pshf[t * 4 + hi] = a * LOG2E;
        }
    }
    __syncthreads();   // ks, vt, pshf visible; only barrier

    // ---------- S^T = mfma(K, Q): lane holds q-row lw ----------
    v4f acc[3][4];
#pragma unroll
    for (int ct = 0; ct < 4; ++ct) {
#pragma unroll
        for (int hi = 0; hi < 3; ++hi) {
            v4f z = {0.f, 0.f, 0.f, 0.f};
            v8s bfr = *(const v8s*)&ks[(ct * 16 + lw) * KS3 + hi * HD + lg * 8];
            acc[hi][ct] = __builtin_amdgcn_mfma_f32_16x16x32_bf16(bfr, aq[hi], z, 0, 0, 0);
        }
    }

    // ---------- bias + exp2 (verified swapped-layout indexing) ----------
    {
        const int q = rowbase + lw;
        const int base2 = ((q >> 3) + 7) * 15 + (q & 7) + 7
                        - ((lg >> 1) * 15 + (lg & 1) * 4);
#pragma unroll
        for (int ct = 0; ct < 4; ++ct)
#pragma unroll
            for (int r = 0; r < 4; ++r) {
                int idx = base2 - ct * 30 - r;
                const float4 bb = *(const float4*)&pshf[idx * 4];
                acc[0][ct][r] = ex2(acc[0][ct][r] + bb.x);
                acc[1][ct][r] = ex2(acc[1][ct][r] + bb.y);
                acc[2][ct][r] = ex2(acc[2][ct][r] + bb.z);
            }
    }

    // ---------- row-sum + normalize into PV A-fragments (in-register) ----------
    unsigned pa[3][2][4];
#pragma unroll
    for (int hi = 0; hi < 3; ++hi) {
        float s = 0.f;
#pragma unroll
        for (int ct = 0; ct < 4; ++ct)
#pragma unroll
            for (int r = 0; r < 4; ++r) s += acc[hi][ct][r];
        s += __shfl_xor(s, 16);
        s += __shfl_xor(s, 32);
        float rv = __builtin_amdgcn_rcpf(s);
#pragma unroll
        for (int kt = 0; kt < 2; ++kt) {
            pa[hi][kt][0] = pkbf(acc[hi][2*kt][0] * rv, acc[hi][2*kt][1] * rv);
            pa[hi][kt][1] = pkbf(acc[hi][2*kt][2] * rv, acc[hi][2*kt][3] * rv);
            pa[hi][kt][2] = pkbf(acc[hi][2*kt+1][0] * rv, acc[hi][2*kt+1][1] * rv);
            pa[hi][kt][3] = pkbf(acc[hi][2*kt+1][2] * rv, acc[hi][2*kt+1][3] * rv);
        }
    }

    // ---------- output offsets ----------
    size_t ooff[4];
#pragma unroll
    for (int r = 0; r < 4; ++r) {
        int n = rowbase + lg * 4 + r;
        ooff[r] = ((size_t)(b * IMG + bh * 8 + (n >> 3)) * IMG
                   + (bw * 8 + (n & 7))) * CDIM;
    }

    // ---------- O = P_norm V ----------
#pragma unroll
    for (int hi = 0; hi < 3; ++hi) {
        v4f acc2[2] = {};
#pragma unroll
        for (int kt = 0; kt < 2; ++kt) {
            v8s pav = *(const v8s*)&pa[hi][kt][0];
#pragma unroll
            for (int dt = 0; dt < 2; ++dt) {
                v8s vb = *(const v8s*)&vt[(hi * HD + dt * 16 + lw) * VTS
                                          + kt * 32 + lg * 8];
                acc2[dt] = __builtin_amdgcn_mfma_f32_16x16x32_bf16(pav, vb, acc2[dt], 0, 0, 0);
            }
        }
        const int h = hg * 3 + hi;
#pragma unroll
        for (int dt = 0; dt < 2; ++dt)
#pragma unroll
            for (int r = 0; r < 4; ++r)
                out[ooff[r] + h * HD + dt * 16 + lw] = acc2[dt][r];
    }
}

extern "C" void kernel_launch(void* const* d_in, const int* in_sizes, int n_in,
                              void* d_out, int out_size, void* d_ws, size_t ws_size,
                              hipStream_t stream) {
    const float* qkv = (const float*)d_in[0];
    win_attn_fused<<<NWIN * 2, 256, 0, stream>>>(
        qkv,
        (const float*)d_in[1], (const float*)d_in[2],
        (const float*)d_in[3], (const float*)d_in[4],
        (const float*)d_in[5], (const float*)d_in[6],
        (const float*)d_in[7], (const float*)d_in[8],
        (const float*)d_in[9], (const float*)d_in[10],
        (const float*)d_in[11], (const float*)d_in[12],
        (const float*)d_in[13], (const float*)d_in[14],
        (float*)d_out);
}